// Round 4
// baseline (194.144 us; speedup 1.0000x reference)
//
#include <hip/hip_runtime.h>

// DynamicGaussianBlur: [B=4, D=160, H=160, W=160, C=2] fp32, sigma [4,3],
// separable 3D gaussian, window 13 (radius 6), SAME zero padding.
// Two passes:
//   A: D-blur register line-walk, float2 in  -> channel-split ws (ws0, ws1)
//   B: fused H+W blur per (b,d,c,half): LDS half-plane slab
//      H-blur (column register-walk) -> LDS round-trip -> W-blur (float4 gather)

#define WSZ 13
#define RAD 6
#define SEG 20
#define NSEG 8

constexpr int BB = 4, DD = 160, HH = 160, WW = 160;
constexpr int R2 = WW;               // row in float2 units      (160)
constexpr int P2 = HH * WW;          // plane (float2 / per-ch float)
constexpr int N2 = DD * HH * WW;     // batch volume per channel
constexpr int NCOL = BB * P2;        // columns for pass A (102,400)
constexpr int NF_C = BB * N2;        // floats per channel (16,384,000)

__device__ __forceinline__ void make_weights(float sig, float* w) {
    const float invd = 1.0f / (2.0f * sig * sig + 1e-7f);
    float s = 0.0f;
#pragma unroll
    for (int k = 0; k < WSZ; ++k) {
        const float loc = (float)(k - RAD);
        w[k] = __expf(-loc * loc * invd);
        s += w[k];
    }
    const float inv = 1.0f / s;
#pragma unroll
    for (int k = 0; k < WSZ; ++k) w[k] *= inv;
}

// ---------------- Pass A: D-blur walk, de-interleave channels ----------------
__global__ __launch_bounds__(256) void blur_d(const float2* __restrict__ in,
                                              float* __restrict__ ws0,
                                              float* __restrict__ ws1,
                                              const float* __restrict__ sigma) {
    const int cid = blockIdx.x * 256 + threadIdx.x;
    const int b   = cid / P2;                        // uniform per block
    const int rem = cid % P2;
    const int h   = rem / 160;
    const int w2  = rem % 160;

    float wgt[WSZ];
    make_weights(sigma[b * 3 + 0], wgt);

    const int base2 = b * N2 + h * R2 + w2;          // float2 index, d=0
    const int p0 = blockIdx.y * SEG;

    float wx[WSZ], wy[WSZ];
#pragma unroll
    for (int k = 0; k < WSZ; ++k) {
        const int q = p0 - RAD + k;
        float2 v = make_float2(0.0f, 0.0f);
        if (q >= 0 && q < DD) v = in[base2 + q * P2];
        wx[k] = v.x; wy[k] = v.y;
    }

#pragma unroll 4
    for (int i = 0; i < SEG; ++i) {
        float ax = 0.0f, ay = 0.0f;
#pragma unroll
        for (int k = 0; k < WSZ; ++k) { ax += wgt[k] * wx[k]; ay += wgt[k] * wy[k]; }
        const int widx = base2 + (p0 + i) * P2;      // same flat layout per channel
        ws0[widx] = ax;
        ws1[widx] = ay;

#pragma unroll
        for (int k = 0; k < WSZ - 1; ++k) { wx[k] = wx[k + 1]; wy[k] = wy[k + 1]; }
        const int q = p0 + i + RAD + 1;
        float2 v = make_float2(0.0f, 0.0f);
        if (q < DD) v = in[base2 + q * P2];
        wx[WSZ - 1] = v.x; wy[WSZ - 1] = v.y;
    }
}

// ---------------- Pass B: fused H+W blur on one (b,d,c) half-plane ----------------
// LDS aliased: slab[92][160] floats (input rows h0-6..h0+85, zero-padded),
// then hbuf[80][176] floats (H-blurred, +8 column shift, zero side stripes).
__global__ __launch_bounds__(512) void blur_hw(const float* __restrict__ ws,
                                               float* __restrict__ outF,
                                               const float* __restrict__ sigma) {
    __shared__ __align__(16) float lds[92 * 160];    // 58,880 B

    const int tid = threadIdx.x;
    const int bx  = blockIdx.x;
    const int c    = bx & 1;                         // fastest: channel pairs co-resident
    const int half = (bx >> 1) & 1;
    const int d    = (bx >> 2) % DD;
    const int b    = bx / (4 * DD);
    const int h0   = half * 80;

    const float* wsc = ws + c * NF_C;
    const int planeF = b * N2 + d * P2;              // per-channel float offset of plane

    float wh[WSZ], ww[WSZ];
    make_weights(sigma[b * 3 + 1], wh);
    make_weights(sigma[b * 3 + 2], ww);

    // ---- load slab: rows h0-6 .. h0+85 (92 rows x 160), float4 coalesced ----
    const float4* ws4 = (const float4*)(wsc + planeF);   // 6400 float4 per plane
    float4* l4 = (float4*)lds;
#pragma unroll
    for (int j = 0; j < 8; ++j) {
        const int f = j * 512 + tid;
        if (f < 92 * 40) {
            const int r = f / 40, q = f % 40;
            const int hh = h0 - 6 + r;
            float4 v = make_float4(0.f, 0.f, 0.f, 0.f);
            if (hh >= 0 && hh < HH) v = ws4[hh * 40 + q];
            l4[f] = v;
        }
    }
    __syncthreads();

    // ---- H-blur: column register-walk. 640 tasks = 160 w x 4 segs of 20 ----
    float o0[SEG], o1[SEG];
    {
        const int w = tid % 160, sg = tid / 160, ob = sg * 20;
        float win[WSZ];
#pragma unroll
        for (int k = 0; k < WSZ - 1; ++k) win[k] = lds[(ob + k) * 160 + w];
#pragma unroll
        for (int i = 0; i < SEG; ++i) {
            win[WSZ - 1] = lds[(ob + i + WSZ - 1) * 160 + w];
            float a = 0.0f;
#pragma unroll
            for (int k = 0; k < WSZ; ++k) a += wh[k] * win[k];
            o0[i] = a;
#pragma unroll
            for (int k = 0; k < WSZ - 1; ++k) win[k] = win[k + 1];
        }
    }
    if (tid < 128) {
        const int task = 512 + tid;
        const int w = task % 160, sg = task / 160, ob = sg * 20;
        float win[WSZ];
#pragma unroll
        for (int k = 0; k < WSZ - 1; ++k) win[k] = lds[(ob + k) * 160 + w];
#pragma unroll
        for (int i = 0; i < SEG; ++i) {
            win[WSZ - 1] = lds[(ob + i + WSZ - 1) * 160 + w];
            float a = 0.0f;
#pragma unroll
            for (int k = 0; k < WSZ; ++k) a += wh[k] * win[k];
            o1[i] = a;
#pragma unroll
            for (int k = 0; k < WSZ - 1; ++k) win[k] = win[k + 1];
        }
    }
    __syncthreads();   // all slab reads done; safe to overwrite as hbuf

    // ---- write hbuf[80][176]: zero stripes cols 0..7 & 168..175, data at +8 ----
#pragma unroll
    for (int j = 0; j < 3; ++j) {
        const int idx = j * 512 + tid;
        if (idx < 80 * 16) {
            const int r = idx / 16, cc = idx % 16;
            const int col = (cc < 8) ? cc : (160 + cc);
            lds[r * 176 + col] = 0.0f;
        }
    }
    {
        const int w = tid % 160, sg = tid / 160, ob = sg * 20;
#pragma unroll
        for (int i = 0; i < SEG; ++i) lds[(ob + i) * 176 + 8 + w] = o0[i];
    }
    if (tid < 128) {
        const int task = 512 + tid;
        const int w = task % 160, sg = task / 160, ob = sg * 20;
#pragma unroll
        for (int i = 0; i < SEG; ++i) lds[(ob + i) * 176 + 8 + w] = o1[i];
    }
    __syncthreads();

    // ---- W-blur: per 4-output quad, 5 aligned float4 LDS reads ----
    // quad q -> row = q/40, w0 = 4*(q%40); fl[i] = value at column (w0-8+i)
#pragma unroll
    for (int j = 0; j < 7; ++j) {
        const int q = j * 512 + tid;
        if (q < 3200) {
            const int row = q / 40;
            const int w0  = (q % 40) * 4;
            const float* hb = &lds[row * 176 + w0];
            const float4 f0 = *(const float4*)(hb);
            const float4 f1 = *(const float4*)(hb + 4);
            const float4 f2 = *(const float4*)(hb + 8);
            const float4 f3 = *(const float4*)(hb + 12);
            const float4 f4v = *(const float4*)(hb + 16);
            const float fl[20] = {f0.x, f0.y, f0.z, f0.w, f1.x, f1.y, f1.z, f1.w,
                                  f2.x, f2.y, f2.z, f2.w, f3.x, f3.y, f3.z, f3.w,
                                  f4v.x, f4v.y, f4v.z, f4v.w};
            const int obase = (planeF + (h0 + row) * 160 + w0) * 2 + c;
#pragma unroll
            for (int jj = 0; jj < 4; ++jj) {
                float a = 0.0f;
#pragma unroll
                for (int k = 0; k < WSZ; ++k) a += ww[k] * fl[jj + k + 2];
                outF[obase + jj * 2] = a;
            }
        }
    }
}

extern "C" void kernel_launch(void* const* d_in, const int* in_sizes, int n_in,
                              void* d_out, int out_size, void* d_ws, size_t ws_size,
                              hipStream_t stream) {
    const float2* img   = (const float2*)d_in[0];
    const float*  sigma = (const float*)d_in[1];
    float* outF = (float*)d_out;
    float* ws0  = (float*)d_ws;
    float* ws1  = ws0 + NF_C;

    blur_d<<<dim3(NCOL / 256, NSEG), dim3(256), 0, stream>>>(img, ws0, ws1, sigma);
    blur_hw<<<dim3(BB * DD * 2 * 2), dim3(512), 0, stream>>>(ws0, outF, sigma);
}

// Round 5
// 119.481 us; speedup vs baseline: 1.6249x; 1.6249x over previous
//
#include <hip/hip_runtime.h>

// DynamicGaussianBlur: [B=4, D=160, H=160, W=160, C=2] fp32, sigma [4,3],
// separable 3D gaussian, window 13 (radius 6), SAME zero padding.
// Two passes, channel-interleaved float2 throughout:
//   A: D-blur register line-walk, in -> ws            (proven round-3 kernel)
//   B: fused H+W blur per (b,d,h-tile): 32x160 f2 LDS slab, H-blur column
//      walk into regs, re-lay as padded hbuf in same LDS, W-blur, store.

#define WSZ 13
#define RAD 6
#define SEGA 40       // pass A: axis segment per thread
#define NSEGA 4

constexpr int BB = 4, DD = 160, HH = 160, WW = 160;
constexpr int R2 = 160;             // row in float2
constexpr int P2 = HH * WW;         // plane in float2 (25,600)
constexpr int N2 = DD * P2;         // batch in float2
constexpr int NCOL = BB * P2;       // pass-A columns (102,400)

#define TB 20                        // pass B: output rows per block
#define SLABR (TB + 12)              // 32 slab rows
#define HBS 172                      // hbuf row stride (6 zero | 160 | 6 zero)

__device__ __forceinline__ void make_weights(float sig, float* w) {
    const float invd = 1.0f / (2.0f * sig * sig + 1e-7f);
    float s = 0.0f;
#pragma unroll
    for (int k = 0; k < WSZ; ++k) {
        const float loc = (float)(k - RAD);
        w[k] = __expf(-loc * loc * invd);
        s += w[k];
    }
    const float inv = 1.0f / s;
#pragma unroll
    for (int k = 0; k < WSZ; ++k) w[k] *= inv;
}

// ---------------- Pass A: D-blur register walk (float2) ----------------
__global__ __launch_bounds__(256) void blur_d(const float2* __restrict__ in,
                                              float2* __restrict__ ws,
                                              const float* __restrict__ sigma) {
    const int cid = blockIdx.x * 256 + threadIdx.x;
    const int b   = cid / P2;                        // uniform per block
    const int rem = cid % P2;
    const int h   = rem / 160;
    const int w2  = rem % 160;

    float wgt[WSZ];
    make_weights(sigma[b * 3 + 0], wgt);

    const int base2 = b * N2 + h * R2 + w2;
    const int p0 = blockIdx.y * SEGA;

    float wx[WSZ], wy[WSZ];
#pragma unroll
    for (int k = 0; k < WSZ; ++k) {
        const int q = p0 - RAD + k;
        float2 v = make_float2(0.0f, 0.0f);
        if (q >= 0 && q < DD) v = in[base2 + q * P2];
        wx[k] = v.x; wy[k] = v.y;
    }

#pragma unroll 4
    for (int i = 0; i < SEGA; ++i) {
        float ax = 0.0f, ay = 0.0f;
#pragma unroll
        for (int k = 0; k < WSZ; ++k) { ax += wgt[k] * wx[k]; ay += wgt[k] * wy[k]; }
        ws[base2 + (p0 + i) * P2] = make_float2(ax, ay);

#pragma unroll
        for (int k = 0; k < WSZ - 1; ++k) { wx[k] = wx[k + 1]; wy[k] = wy[k + 1]; }
        const int q = p0 + i + RAD + 1;
        float2 v = make_float2(0.0f, 0.0f);
        if (q < DD) v = in[base2 + q * P2];
        wx[WSZ - 1] = v.x; wy[WSZ - 1] = v.y;
    }
}

// ---------------- Pass B: fused H+W blur, one (b,d,h-tile) per block ----------------
__global__ __launch_bounds__(320) void blur_hw(const float2* __restrict__ ws,
                                               float2* __restrict__ out,
                                               const float* __restrict__ sigma) {
    __shared__ __align__(16) float2 lds[SLABR * R2];   // 5120 f2 = 40,960 B

    const int tid  = threadIdx.x;
    const int bx   = blockIdx.x;
    const int tile = bx & 7;                 // 8 h-tiles of 20 rows
    const int d    = (bx >> 3) % DD;
    const int b    = bx / (8 * DD);
    const int h0   = tile * TB;

    float wh[WSZ];
    make_weights(sigma[b * 3 + 1], wh);

    const float2* plane = ws + b * N2 + d * P2;

    // ---- load slab rows h0-6 .. h0+25 (32 x 160 f2) as float4: 2560 f4, 8/thread ----
    const float4* p4 = (const float4*)plane;           // 80 f4 per row
    float4* l4 = (float4*)lds;
#pragma unroll
    for (int j = 0; j < 8; ++j) {
        const int f = j * 320 + tid;                   // 0..2559
        const int r = f / 80, q = f % 80;
        const int hh = h0 - 6 + r;
        float4 v = make_float4(0.f, 0.f, 0.f, 0.f);
        if (hh >= 0 && hh < HH) v = p4[hh * 80 + q];
        l4[f] = v;
    }
    __syncthreads();

    // ---- H-blur: one column-walk per thread. w = tid%160, rows r0..r0+9 ----
    float2 o[10];
    {
        const int w  = tid % 160;
        const int r0 = (tid / 160) * 10;
        float2 win[WSZ];
#pragma unroll
        for (int k = 0; k < WSZ - 1; ++k) win[k] = lds[(r0 + k) * R2 + w];
#pragma unroll
        for (int i = 0; i < 10; ++i) {
            win[WSZ - 1] = lds[(r0 + i + WSZ - 1) * R2 + w];
            float ax = 0.0f, ay = 0.0f;
#pragma unroll
            for (int k = 0; k < WSZ; ++k) { ax += wh[k] * win[k].x; ay += wh[k] * win[k].y; }
            o[i] = make_float2(ax, ay);
#pragma unroll
            for (int k = 0; k < WSZ - 1; ++k) win[k] = win[k + 1];
        }
    }
    __syncthreads();   // all slab reads done; reuse LDS as hbuf[20][172]

    // ---- write hbuf: zero stripes + data shifted +6 ----
    float2* hb = lds;
    if (tid < 240) {                                   // 20 rows x 12 stripe f2
        const int r = tid / 12, c = tid % 12;
        const int col = (c < 6) ? c : (160 + c);
        hb[r * HBS + col] = make_float2(0.0f, 0.0f);
    }
    {
        const int w  = tid % 160;
        const int r0 = (tid / 160) * 10;
#pragma unroll
        for (int i = 0; i < 10; ++i) hb[(r0 + i) * HBS + 6 + w] = o[i];
    }
    __syncthreads();

    // ---- W-blur: 3200 outputs, o = j*320 + tid (coalesced stores) ----
    float ww[WSZ];
    make_weights(sigma[b * 3 + 2], ww);

    float2* oplane = out + b * N2 + d * P2 + h0 * R2;
#pragma unroll
    for (int j = 0; j < 10; ++j) {
        const int oidx = j * 320 + tid;
        const int r = oidx / 160, w = oidx % 160;
        const float2* src = &hb[r * HBS + w];          // cols w..w+12 (data at +6)
        float ax = 0.0f, ay = 0.0f;
#pragma unroll
        for (int k = 0; k < WSZ; ++k) { const float2 v = src[k]; ax += ww[k] * v.x; ay += ww[k] * v.y; }
        oplane[oidx] = make_float2(ax, ay);
    }
}

extern "C" void kernel_launch(void* const* d_in, const int* in_sizes, int n_in,
                              void* d_out, int out_size, void* d_ws, size_t ws_size,
                              hipStream_t stream) {
    const float2* img   = (const float2*)d_in[0];
    const float*  sigma = (const float*)d_in[1];
    float2* out = (float2*)d_out;
    float2* ws  = (float2*)d_ws;

    blur_d<<<dim3(NCOL / 256, NSEGA), dim3(256), 0, stream>>>(img, ws, sigma);
    blur_hw<<<dim3(BB * DD * 8), dim3(320), 0, stream>>>(ws, out, sigma);
}